// Round 17
// baseline (97.009 us; speedup 1.0000x reference)
//
#include <hip/hip_runtime.h>

#define N_CLS 8192
#define DIM   2048          // feature dim; M = Xn^T Xn is DIM x DIM
#define XTROW 4096          // xt row bytes: 8192 fp4 elems / 2
#define BKB   128           // K-tile bytes per row = 256 fp4 elems
#define NBT   16            // DIM/128 tile grid
#define NTRI  136           // NBT*(NBT+1)/2 triangular 128x128 tiles
#define NCH   4             // K chunks (8192 elems -> 4 x 2048)
#define NKT   8             // K-tiles per chunk (1024 B / 128 B)
#define MSLOT 16384         // u16 elems per partial 128x128 tile (32 KB)
#define NQS   (NTRI * 4 + 8)   // qscombine grid (544 q-blocks + 8 s-blocks)

typedef __attribute__((ext_vector_type(16))) float f32x16;
typedef __attribute__((ext_vector_type(8)))  int   i32x8;

__device__ __forceinline__ void load16(const char* g, char* l) {
    __builtin_amdgcn_global_load_lds(
        (const __attribute__((address_space(1))) void*)g,
        (__attribute__((address_space(3))) void*)l, 16, 0, 0);
}

__device__ __forceinline__ unsigned short f2bf(float f) {
    union { float f; unsigned u; } a; a.f = f;
    return (unsigned short)((a.u + 0x7fffu + ((a.u >> 16) & 1u)) >> 16);
}
__device__ __forceinline__ float bf2f(unsigned short u) {
    union { unsigned u; float f; } a; a.u = ((unsigned)u) << 16;
    return a.f;
}
// ---- e2m1 encode: nearest of {0,.5,1,1.5,2,3,4,6} with sign ----
__device__ __forceinline__ unsigned enc1(float v, float sc) {
    float a = fabsf(v) * sc;
    unsigned c = (a >= 0.25f) + (a >= 0.75f) + (a >= 1.25f) + (a >= 1.75f) +
                 (a >= 2.5f)  + (a >= 3.5f)  + (a >= 5.0f);
    return c | ((__float_as_uint(v) >> 28) & 8u);
}

// ---------------- kernel 1: per-row 1/||row|| (proven r8) ----------------
__global__ __launch_bounds__(256) void row_norms(const float* __restrict__ x,
                                                 float* __restrict__ inv) {
    const int wid = threadIdx.x >> 6, lane = threadIdx.x & 63;
    const int row = blockIdx.x * 4 + wid;
    const float4* xr = reinterpret_cast<const float4*>(x + (size_t)row * DIM);
    float s = 0.0f;
#pragma unroll
    for (int k = 0; k < 8; ++k) {
        float4 v = xr[lane + 64 * k];
        s += v.x*v.x + v.y*v.y + v.z*v.z + v.w*v.w;
    }
#pragma unroll
    for (int off = 32; off > 0; off >>= 1) s += __shfl_down(s, off);
    if (lane == 0) inv[row] = 1.0f / fmaxf(sqrtf(s), 1e-12f);
}

// ---- kernel 2: transpose+quantize, nibble-packed LDS (proven r15) ----
__global__ __launch_bounds__(256) void transpose_quant(const float* __restrict__ x,
                                                       const float* __restrict__ inv,
                                                       unsigned char* __restrict__ xt,
                                                       float* __restrict__ Spart) {
    __shared__ unsigned short nib[128][40];   // [row][col-group]; 4 cols per u16
    __shared__ float invs[128];
    __shared__ float sred[4][128];
    const int ic = blockIdx.x, dc = blockIdx.y;
    const int t = threadIdx.x;
    if (t < 128) invs[t] = inv[ic * 128 + t];
    __syncthreads();
    float sc0 = 0.f, sc1 = 0.f, sc2 = 0.f, sc3 = 0.f;
    const int cg = t & 31;                 // loop-invariant column group (4 cols)
#pragma unroll
    for (int it = 0; it < 16; ++it) {
        const int r = it * 8 + (t >> 5);   // 0..127
        float4 v = *reinterpret_cast<const float4*>(
            x + (size_t)(ic * 128 + r) * DIM + dc * 128 + cg * 4);
        const float iv = invs[r];
        float n0 = v.x * iv, n1 = v.y * iv, n2 = v.z * iv, n3 = v.w * iv;
        nib[r][cg] = (unsigned short)(enc1(n0, 64.0f) | (enc1(n1, 64.0f) << 4) |
                                      (enc1(n2, 64.0f) << 8) | (enc1(n3, 64.0f) << 12));
        sc0 += n0; sc1 += n1; sc2 += n2; sc3 += n3;
    }
    sc0 += __shfl_down(sc0, 32); sc1 += __shfl_down(sc1, 32);
    sc2 += __shfl_down(sc2, 32); sc3 += __shfl_down(sc3, 32);
    const int lane = t & 63, w = t >> 6;
    if (lane < 32) {
        sred[w][lane * 4 + 0] = sc0; sred[w][lane * 4 + 1] = sc1;
        sred[w][lane * 4 + 2] = sc2; sred[w][lane * 4 + 3] = sc3;
    }
    __syncthreads();
    if (t < 128)
        Spart[(size_t)ic * DIM + dc * 128 + t] =
            sred[0][t] + sred[1][t] + sred[2][t] + sred[3][t];

    // gather: thread owns (d, half); assemble 32 bytes along i for fixed d
    const int d = t & 127, half = t >> 7, dg = d >> 2, sh = (d & 3) * 4;
    unsigned wv[8];
#pragma unroll
    for (int j = 0; j < 8; ++j) {
        unsigned wd = 0;
#pragma unroll
        for (int b = 0; b < 4; ++b) {
            const int i0 = half * 64 + (j * 4 + b) * 2;
            unsigned lo = (nib[i0][dg] >> sh) & 0xFu;
            unsigned hi = (nib[i0 + 1][dg] >> sh) & 0xFu;
            wd |= (lo | (hi << 4)) << (8 * b);
        }
        wv[j] = wd;
    }
    const size_t off = (size_t)(dc * 128 + d) * XTROW + ic * 64 + half * 32;
    *reinterpret_cast<int4*>(xt + off)      = make_int4((int)wv[0], (int)wv[1], (int)wv[2], (int)wv[3]);
    *reinterpret_cast<int4*>(xt + off + 16) = make_int4((int)wv[4], (int)wv[5], (int)wv[6], (int)wv[7]);
}

// read one 16-byte (K=64, fp4) fragment from a swizzled LDS row; dup into both halves
__device__ __forceinline__ i32x8 rdfrag4(const char* rowp, int cc, int swz) {
    int4 d = *reinterpret_cast<const int4*>(rowp + (((cc) ^ swz) << 4));
    i32x8 r;
    r[0] = d.x; r[1] = d.y; r[2] = d.z; r[3] = d.w;
    r[4] = d.x; r[5] = d.y; r[6] = d.z; r[7] = d.w;
    return r;
}
#define MFMA4(A, B, C) __builtin_amdgcn_mfma_scale_f32_32x32x64_f8f6f4( \
    (A), (B), (C), 4, 4, 0, 0x7F7F7F7F, 0, 0x7F7F7F7F)

// ---- kernel 3: partial M-tile SYRK, K-split x4, bf16 out (proven r15) + XCD swizzle ----
__global__ __launch_bounds__(256) void msyrk_part(const char* __restrict__ xt,
                                                  unsigned short* __restrict__ Mpart) {
    __shared__ __align__(16) char As[128 * BKB];   // 16 KiB
    __shared__ __align__(16) char Bs[128 * BKB];   // 16 KiB

    // XCD swizzle: 544 = 8 x 68; a tile's 4 chunks land on one XCD's L2
    const int swb = (int)((blockIdx.x & 7) * (NTRI * NCH / 8) + (blockIdx.x >> 3));
    const int tile = swb >> 2, ch = swb & 3;
    int bi = 0, rem = tile;                     // triangle decode, bi <= bj
    while (rem >= NBT - bi) { rem -= NBT - bi; ++bi; }
    const int bj = bi + rem;

    const int tid = threadIdx.x;
    const int lane = tid & 63, wid = tid >> 6;
    const int wr = wid >> 1, wc = wid & 1;      // wave grid 2 x 2, each 64x64

    const int srow = lane >> 3;
    const int gch  = ((lane & 7) ^ srow) << 4;
    const char* gA = xt + (size_t)(bi * 128 + wid * 32 + srow) * XTROW + ch * 1024 + gch;
    const char* gB = xt + (size_t)(bj * 128 + wid * 32 + srow) * XTROW + ch * 1024 + gch;

    const int lr = lane & 31, hi = lane >> 5, swz = lane & 7;
    const char* arow = As + (wr * 64 + lr) * BKB;
    const char* brow = Bs + (wc * 64 + lr) * BKB;

    f32x16 acc[2][2];
#pragma unroll
    for (int m = 0; m < 2; ++m)
#pragma unroll
        for (int n = 0; n < 2; ++n)
#pragma unroll
            for (int r = 0; r < 16; ++r) acc[m][n][r] = 0.0f;

    for (int t = 0; t < NKT; ++t) {
#pragma unroll
        for (int q = 0; q < 4; ++q)
            load16(gA + (size_t)(q * 8) * XTROW + t * BKB, &As[wid * 4096 + q * 1024]);
#pragma unroll
        for (int q = 0; q < 4; ++q)
            load16(gB + (size_t)(q * 8) * XTROW + t * BKB, &Bs[wid * 4096 + q * 1024]);
        __syncthreads();
#pragma unroll
        for (int s = 0; s < 4; ++s) {
            i32x8 af[2], bf[2];
#pragma unroll
            for (int m = 0; m < 2; ++m)
                af[m] = rdfrag4(arow + m * 32 * BKB, 2 * s + hi, swz);
#pragma unroll
            for (int n = 0; n < 2; ++n)
                bf[n] = rdfrag4(brow + n * 32 * BKB, 2 * s + hi, swz);
#pragma unroll
            for (int m = 0; m < 2; ++m)
#pragma unroll
                for (int n = 0; n < 2; ++n)
                    acc[m][n] = MFMA4(af[m], bf[n], acc[m][n]);
        }
        __syncthreads();
    }

    unsigned short* outp = Mpart + (size_t)(tile * NCH + ch) * MSLOT;
#pragma unroll
    for (int m = 0; m < 2; ++m)
#pragma unroll
        for (int n = 0; n < 2; ++n)
#pragma unroll
            for (int rq = 0; rq < 4; ++rq) {
                ushort4 v;
                v.x = f2bf(acc[m][n][rq * 4 + 0]);
                v.y = f2bf(acc[m][n][rq * 4 + 1]);
                v.z = f2bf(acc[m][n][rq * 4 + 2]);
                v.w = f2bf(acc[m][n][rq * 4 + 3]);
                *reinterpret_cast<ushort4*>(outp + ((m * 2 + n) * 4 + rq) * 1024 + tid * 4) = v;
            }
}

// ---- kernel 4: qcombine + scombine + fused last-block finalize ----
__global__ __launch_bounds__(256) void qscombine(const unsigned short* __restrict__ Mpart,
                                                 const float* __restrict__ Spart,
                                                 float* __restrict__ qpart,
                                                 float* __restrict__ S,
                                                 unsigned int* __restrict__ ticket,
                                                 float* __restrict__ out) {
    const int t = threadIdx.x;
    if (blockIdx.x >= NTRI * 4) {               // scombine: 8 blocks
        const int d = (blockIdx.x - NTRI * 4) * 256 + t;
        float s = 0.0f;
        for (int ic = 0; ic < 64; ++ic) s += Spart[(size_t)ic * DIM + d];
        S[d] = s;
    } else {
        const int tile = blockIdx.x >> 2, q4 = blockIdx.x & 3;
        int bi = 0, rem = tile;
        while (rem >= NBT - bi) { rem -= NBT - bi; ++bi; }
        const int bj = bi + rem;
        const float w = (bi == bj) ? 1.0f : 2.0f;
        const float inv = 1.0f / 4096.0f;       // raw = 4096 * M (scale 64^2)

        const unsigned short* base = Mpart + (size_t)tile * NCH * MSLOT;
        float s = 0.0f;
#pragma unroll
        for (int k = 0; k < 4; ++k) {
            const int p = q4 * 4096 + k * 1024 + t * 4;
            ushort4 a0 = *reinterpret_cast<const ushort4*>(base + 0 * MSLOT + p);
            ushort4 a1 = *reinterpret_cast<const ushort4*>(base + 1 * MSLOT + p);
            ushort4 a2 = *reinterpret_cast<const ushort4*>(base + 2 * MSLOT + p);
            ushort4 a3 = *reinterpret_cast<const ushort4*>(base + 3 * MSLOT + p);
            float vx = (bf2f(a0.x) + bf2f(a1.x) + bf2f(a2.x) + bf2f(a3.x)) * inv;
            float vy = (bf2f(a0.y) + bf2f(a1.y) + bf2f(a2.y) + bf2f(a3.y)) * inv;
            float vz = (bf2f(a0.z) + bf2f(a1.z) + bf2f(a2.z) + bf2f(a3.z)) * inv;
            float vw = (bf2f(a0.w) + bf2f(a1.w) + bf2f(a2.w) + bf2f(a3.w)) * inv;
            s += vx * vx + vy * vy + vz * vz + vw * vw;
        }
#pragma unroll
        for (int off = 32; off > 0; off >>= 1) s += __shfl_down(s, off);
        __shared__ float red[4];
        if ((t & 63) == 0) red[t >> 6] = s;
        __syncthreads();
        if (t == 0)
            qpart[blockIdx.x] = w * (red[0] + red[1] + red[2] + red[3]);
    }

    // ---- last-block finalize (deterministic: fixed-order reduce by one block) ----
    __threadfence();
    __shared__ unsigned int last;
    if (t == 0) last = atomicAdd(ticket, 1u);
    __syncthreads();
    if (last != NQS - 1) return;
    __threadfence();                            // acquire all blocks' writes

    float q = 0.0f;
    for (int i = t; i < NTRI * 4; i += 256) q += qpart[i];
    float s2 = 0.0f;
#pragma unroll
    for (int k = 0; k < 8; ++k) {
        float v = S[t + 256 * k];
        s2 += v * v;
    }
#pragma unroll
    for (int off = 32; off > 0; off >>= 1) {
        q  += __shfl_down(q, off);
        s2 += __shfl_down(s2, off);
    }
    __shared__ float redq[4], reds[4];
    if ((t & 63) == 0) { redq[t >> 6] = q; reds[t >> 6] = s2; }
    __syncthreads();
    if (t == 0) {
        double Q  = (double)redq[0] + redq[1] + redq[2] + redq[3];
        double S2 = (double)reds[0] + reds[1] + reds[2] + reds[3];
        const double N = 8192.0, NN1 = 8192.0 * 8191.0;
        out[0] = (float)((N + exp(-2.0) * (NN1 + 2.0 * (S2 - N) + 2.0 * (Q - N))) / NN1);
    }
}

extern "C" void kernel_launch(void* const* d_in, const int* in_sizes, int n_in,
                              void* d_out, int out_size, void* d_ws, size_t ws_size,
                              hipStream_t stream) {
    const float* x = (const float*)d_in[0];
    float* out = (float*)d_out;
    // ws layout: xt 8MB | inv 32KB | Spart 512KB | S 8KB | Mpart(bf16) 17.8MB | qpart | ticket
    unsigned char* xt = (unsigned char*)d_ws;
    float* inv   = (float*)((char*)d_ws + (size_t)DIM * XTROW);
    float* Spart = inv + N_CLS;
    float* S     = Spart + (size_t)64 * DIM;
    unsigned short* Mpart = (unsigned short*)(S + DIM);
    float* qpart = (float*)(Mpart + (size_t)NTRI * NCH * MSLOT);
    unsigned int* ticket = (unsigned int*)(qpart + NQS);

    hipMemsetAsync(ticket, 0, sizeof(unsigned int), stream);
    row_norms<<<N_CLS / 4, 256, 0, stream>>>(x, inv);
    transpose_quant<<<dim3(64, 16), 256, 0, stream>>>(x, inv, xt, Spart);
    msyrk_part<<<NTRI * NCH, 256, 0, stream>>>((const char*)xt, Mpart);
    qscombine<<<NQS, 256, 0, stream>>>(Mpart, Spart, qpart, S, ticket, out);
}

// Round 18
// 56.569 us; speedup vs baseline: 1.7149x; 1.7149x over previous
//
#include <hip/hip_runtime.h>

#define N_CLS 8192
#define DIM   2048          // feature dim; M = Xn^T Xn is DIM x DIM
#define XTROW 4096          // xt row bytes: 8192 fp4 elems / 2
#define BKB   128           // K-tile bytes per row = 256 fp4 elems
#define NBT   16            // DIM/128 tile grid
#define NTRI  136           // NBT*(NBT+1)/2 triangular 128x128 tiles
#define NCH   4             // K chunks (8192 elems -> 4 x 2048)
#define NKT   8             // K-tiles per chunk (1024 B / 128 B)
#define MSLOT 16384         // u16 elems per partial 128x128 tile (32 KB)

typedef __attribute__((ext_vector_type(16))) float f32x16;
typedef __attribute__((ext_vector_type(8)))  int   i32x8;

__device__ __forceinline__ void load16(const char* g, char* l) {
    __builtin_amdgcn_global_load_lds(
        (const __attribute__((address_space(1))) void*)g,
        (__attribute__((address_space(3))) void*)l, 16, 0, 0);
}

__device__ __forceinline__ unsigned short f2bf(float f) {
    union { float f; unsigned u; } a; a.f = f;
    return (unsigned short)((a.u + 0x7fffu + ((a.u >> 16) & 1u)) >> 16);
}
__device__ __forceinline__ float bf2f(unsigned short u) {
    union { unsigned u; float f; } a; a.u = ((unsigned)u) << 16;
    return a.f;
}
// ---- e2m1 encode: nearest of {0,.5,1,1.5,2,3,4,6} with sign ----
__device__ __forceinline__ unsigned enc1(float v, float sc) {
    float a = fabsf(v) * sc;
    unsigned c = (a >= 0.25f) + (a >= 0.75f) + (a >= 1.25f) + (a >= 1.75f) +
                 (a >= 2.5f)  + (a >= 3.5f)  + (a >= 5.0f);
    return c | ((__float_as_uint(v) >> 28) & 8u);
}

// ---------------- kernel 1: per-row 1/||row|| (proven r8) ----------------
__global__ __launch_bounds__(256) void row_norms(const float* __restrict__ x,
                                                 float* __restrict__ inv) {
    const int wid = threadIdx.x >> 6, lane = threadIdx.x & 63;
    const int row = blockIdx.x * 4 + wid;
    const float4* xr = reinterpret_cast<const float4*>(x + (size_t)row * DIM);
    float s = 0.0f;
#pragma unroll
    for (int k = 0; k < 8; ++k) {
        float4 v = xr[lane + 64 * k];
        s += v.x*v.x + v.y*v.y + v.z*v.z + v.w*v.w;
    }
#pragma unroll
    for (int off = 32; off > 0; off >>= 1) s += __shfl_down(s, off);
    if (lane == 0) inv[row] = 1.0f / fmaxf(sqrtf(s), 1e-12f);
}

// ---- kernel 2: transpose+quantize, nibble-packed LDS (proven r15) ----
__global__ __launch_bounds__(256) void transpose_quant(const float* __restrict__ x,
                                                       const float* __restrict__ inv,
                                                       unsigned char* __restrict__ xt,
                                                       float* __restrict__ Spart) {
    __shared__ unsigned short nib[128][40];   // [row][col-group]; 4 cols per u16
    __shared__ float invs[128];
    __shared__ float sred[4][128];
    const int ic = blockIdx.x, dc = blockIdx.y;
    const int t = threadIdx.x;
    if (t < 128) invs[t] = inv[ic * 128 + t];
    __syncthreads();
    float sc0 = 0.f, sc1 = 0.f, sc2 = 0.f, sc3 = 0.f;
    const int cg = t & 31;                 // loop-invariant column group (4 cols)
#pragma unroll
    for (int it = 0; it < 16; ++it) {
        const int r = it * 8 + (t >> 5);   // 0..127
        float4 v = *reinterpret_cast<const float4*>(
            x + (size_t)(ic * 128 + r) * DIM + dc * 128 + cg * 4);
        const float iv = invs[r];
        float n0 = v.x * iv, n1 = v.y * iv, n2 = v.z * iv, n3 = v.w * iv;
        nib[r][cg] = (unsigned short)(enc1(n0, 64.0f) | (enc1(n1, 64.0f) << 4) |
                                      (enc1(n2, 64.0f) << 8) | (enc1(n3, 64.0f) << 12));
        sc0 += n0; sc1 += n1; sc2 += n2; sc3 += n3;
    }
    sc0 += __shfl_down(sc0, 32); sc1 += __shfl_down(sc1, 32);
    sc2 += __shfl_down(sc2, 32); sc3 += __shfl_down(sc3, 32);
    const int lane = t & 63, w = t >> 6;
    if (lane < 32) {
        sred[w][lane * 4 + 0] = sc0; sred[w][lane * 4 + 1] = sc1;
        sred[w][lane * 4 + 2] = sc2; sred[w][lane * 4 + 3] = sc3;
    }
    __syncthreads();
    if (t < 128)
        Spart[(size_t)ic * DIM + dc * 128 + t] =
            sred[0][t] + sred[1][t] + sred[2][t] + sred[3][t];

    // gather: thread owns (d, half); assemble 32 bytes along i for fixed d
    const int d = t & 127, half = t >> 7, dg = d >> 2, sh = (d & 3) * 4;
    unsigned wv[8];
#pragma unroll
    for (int j = 0; j < 8; ++j) {
        unsigned wd = 0;
#pragma unroll
        for (int b = 0; b < 4; ++b) {
            const int i0 = half * 64 + (j * 4 + b) * 2;
            unsigned lo = (nib[i0][dg] >> sh) & 0xFu;
            unsigned hi = (nib[i0 + 1][dg] >> sh) & 0xFu;
            wd |= (lo | (hi << 4)) << (8 * b);
        }
        wv[j] = wd;
    }
    const size_t off = (size_t)(dc * 128 + d) * XTROW + ic * 64 + half * 32;
    *reinterpret_cast<int4*>(xt + off)      = make_int4((int)wv[0], (int)wv[1], (int)wv[2], (int)wv[3]);
    *reinterpret_cast<int4*>(xt + off + 16) = make_int4((int)wv[4], (int)wv[5], (int)wv[6], (int)wv[7]);
}

// read one 16-byte (K=64, fp4) fragment from a swizzled LDS row; dup into both halves
__device__ __forceinline__ i32x8 rdfrag4(const char* rowp, int cc, int swz) {
    int4 d = *reinterpret_cast<const int4*>(rowp + (((cc) ^ swz) << 4));
    i32x8 r;
    r[0] = d.x; r[1] = d.y; r[2] = d.z; r[3] = d.w;
    r[4] = d.x; r[5] = d.y; r[6] = d.z; r[7] = d.w;
    return r;
}
#define MFMA4(A, B, C) __builtin_amdgcn_mfma_scale_f32_32x32x64_f8f6f4( \
    (A), (B), (C), 4, 4, 0, 0x7F7F7F7F, 0, 0x7F7F7F7F)

// ---- kernel 3: partial M-tile SYRK, K-split x4, bf16 out (proven r15) + XCD swizzle ----
__global__ __launch_bounds__(256) void msyrk_part(const char* __restrict__ xt,
                                                  unsigned short* __restrict__ Mpart) {
    __shared__ __align__(16) char As[128 * BKB];   // 16 KiB
    __shared__ __align__(16) char Bs[128 * BKB];   // 16 KiB

    // XCD swizzle: 544 = 8 x 68; a tile's 4 chunks land on one XCD's L2
    const int swb = (int)((blockIdx.x & 7) * (NTRI * NCH / 8) + (blockIdx.x >> 3));
    const int tile = swb >> 2, ch = swb & 3;
    int bi = 0, rem = tile;                     // triangle decode, bi <= bj
    while (rem >= NBT - bi) { rem -= NBT - bi; ++bi; }
    const int bj = bi + rem;

    const int tid = threadIdx.x;
    const int lane = tid & 63, wid = tid >> 6;
    const int wr = wid >> 1, wc = wid & 1;      // wave grid 2 x 2, each 64x64

    const int srow = lane >> 3;
    const int gch  = ((lane & 7) ^ srow) << 4;
    const char* gA = xt + (size_t)(bi * 128 + wid * 32 + srow) * XTROW + ch * 1024 + gch;
    const char* gB = xt + (size_t)(bj * 128 + wid * 32 + srow) * XTROW + ch * 1024 + gch;

    const int lr = lane & 31, hi = lane >> 5, swz = lane & 7;
    const char* arow = As + (wr * 64 + lr) * BKB;
    const char* brow = Bs + (wc * 64 + lr) * BKB;

    f32x16 acc[2][2];
#pragma unroll
    for (int m = 0; m < 2; ++m)
#pragma unroll
        for (int n = 0; n < 2; ++n)
#pragma unroll
            for (int r = 0; r < 16; ++r) acc[m][n][r] = 0.0f;

    for (int t = 0; t < NKT; ++t) {
#pragma unroll
        for (int q = 0; q < 4; ++q)
            load16(gA + (size_t)(q * 8) * XTROW + t * BKB, &As[wid * 4096 + q * 1024]);
#pragma unroll
        for (int q = 0; q < 4; ++q)
            load16(gB + (size_t)(q * 8) * XTROW + t * BKB, &Bs[wid * 4096 + q * 1024]);
        __syncthreads();
#pragma unroll
        for (int s = 0; s < 4; ++s) {
            i32x8 af[2], bf[2];
#pragma unroll
            for (int m = 0; m < 2; ++m)
                af[m] = rdfrag4(arow + m * 32 * BKB, 2 * s + hi, swz);
#pragma unroll
            for (int n = 0; n < 2; ++n)
                bf[n] = rdfrag4(brow + n * 32 * BKB, 2 * s + hi, swz);
#pragma unroll
            for (int m = 0; m < 2; ++m)
#pragma unroll
                for (int n = 0; n < 2; ++n)
                    acc[m][n] = MFMA4(af[m], bf[n], acc[m][n]);
        }
        __syncthreads();
    }

    unsigned short* outp = Mpart + (size_t)(tile * NCH + ch) * MSLOT;
#pragma unroll
    for (int m = 0; m < 2; ++m)
#pragma unroll
        for (int n = 0; n < 2; ++n)
#pragma unroll
            for (int rq = 0; rq < 4; ++rq) {
                ushort4 v;
                v.x = f2bf(acc[m][n][rq * 4 + 0]);
                v.y = f2bf(acc[m][n][rq * 4 + 1]);
                v.z = f2bf(acc[m][n][rq * 4 + 2]);
                v.w = f2bf(acc[m][n][rq * 4 + 3]);
                *reinterpret_cast<ushort4*>(outp + ((m * 2 + n) * 4 + rq) * 1024 + tid * 4) = v;
            }
}

// ---- kernel 4: qcombine (blocks < NTRI*4) + scombine (blocks >= NTRI*4), proven r15 ----
__global__ __launch_bounds__(256) void qscombine(const unsigned short* __restrict__ Mpart,
                                                 const float* __restrict__ Spart,
                                                 float* __restrict__ qpart,
                                                 float* __restrict__ S) {
    if (blockIdx.x >= NTRI * 4) {               // scombine: 8 blocks
        const int d = (blockIdx.x - NTRI * 4) * 256 + threadIdx.x;
        float s = 0.0f;
        for (int ic = 0; ic < 64; ++ic) s += Spart[(size_t)ic * DIM + d];
        S[d] = s;
        return;
    }
    const int tile = blockIdx.x >> 2, q4 = blockIdx.x & 3;
    int bi = 0, rem = tile;
    while (rem >= NBT - bi) { rem -= NBT - bi; ++bi; }
    const int bj = bi + rem;
    const float w = (bi == bj) ? 1.0f : 2.0f;
    const float inv = 1.0f / 4096.0f;           // raw = 4096 * M (scale 64^2)

    const unsigned short* base = Mpart + (size_t)tile * NCH * MSLOT;
    float s = 0.0f;
#pragma unroll
    for (int k = 0; k < 4; ++k) {
        const int p = q4 * 4096 + k * 1024 + threadIdx.x * 4;
        ushort4 a0 = *reinterpret_cast<const ushort4*>(base + 0 * MSLOT + p);
        ushort4 a1 = *reinterpret_cast<const ushort4*>(base + 1 * MSLOT + p);
        ushort4 a2 = *reinterpret_cast<const ushort4*>(base + 2 * MSLOT + p);
        ushort4 a3 = *reinterpret_cast<const ushort4*>(base + 3 * MSLOT + p);
        float vx = (bf2f(a0.x) + bf2f(a1.x) + bf2f(a2.x) + bf2f(a3.x)) * inv;
        float vy = (bf2f(a0.y) + bf2f(a1.y) + bf2f(a2.y) + bf2f(a3.y)) * inv;
        float vz = (bf2f(a0.z) + bf2f(a1.z) + bf2f(a2.z) + bf2f(a3.z)) * inv;
        float vw = (bf2f(a0.w) + bf2f(a1.w) + bf2f(a2.w) + bf2f(a3.w)) * inv;
        s += vx * vx + vy * vy + vz * vz + vw * vw;
    }
#pragma unroll
    for (int off = 32; off > 0; off >>= 1) s += __shfl_down(s, off);
    __shared__ float red[4];
    if ((threadIdx.x & 63) == 0) red[threadIdx.x >> 6] = s;
    __syncthreads();
    if (threadIdx.x == 0)
        qpart[blockIdx.x] = w * (red[0] + red[1] + red[2] + red[3]);
}

// ---------------- kernel 5: finalize (proven r8 formula) ----------------
__global__ __launch_bounds__(256) void finalize(const float* __restrict__ qpart,
                                                const float* __restrict__ S,
                                                float* __restrict__ out) {
    const int t = threadIdx.x;
    float q = 0.0f;
    for (int i = t; i < NTRI * 4; i += 256) q += qpart[i];
    float s2 = 0.0f;
#pragma unroll
    for (int k = 0; k < 8; ++k) {
        float v = S[t + 256 * k];
        s2 += v * v;
    }
#pragma unroll
    for (int off = 32; off > 0; off >>= 1) {
        q  += __shfl_down(q, off);
        s2 += __shfl_down(s2, off);
    }
    __shared__ float redq[4], reds[4];
    if ((t & 63) == 0) { redq[t >> 6] = q; reds[t >> 6] = s2; }
    __syncthreads();
    if (t == 0) {
        double Q  = (double)redq[0] + redq[1] + redq[2] + redq[3];
        double S2 = (double)reds[0] + reds[1] + reds[2] + reds[3];
        const double N = 8192.0, NN1 = 8192.0 * 8191.0;
        double ans = (N + exp(-2.0) * (NN1 + 2.0 * (S2 - N) + 2.0 * (Q - N))) / NN1;
        out[0] = (float)ans;
    }
}

extern "C" void kernel_launch(void* const* d_in, const int* in_sizes, int n_in,
                              void* d_out, int out_size, void* d_ws, size_t ws_size,
                              hipStream_t stream) {
    const float* x = (const float*)d_in[0];
    float* out = (float*)d_out;
    // ws layout: xt 8MB | inv 32KB | Spart 512KB | S 8KB | Mpart(bf16) 17.8MB | qpart
    unsigned char* xt = (unsigned char*)d_ws;
    float* inv   = (float*)((char*)d_ws + (size_t)DIM * XTROW);
    float* Spart = inv + N_CLS;
    float* S     = Spart + (size_t)64 * DIM;
    unsigned short* Mpart = (unsigned short*)(S + DIM);
    float* qpart = (float*)(Mpart + (size_t)NTRI * NCH * MSLOT);

    row_norms<<<N_CLS / 4, 256, 0, stream>>>(x, inv);
    transpose_quant<<<dim3(64, 16), 256, 0, stream>>>(x, inv, xt, Spart);
    msyrk_part<<<NTRI * NCH, 256, 0, stream>>>((const char*)xt, Mpart);
    qscombine<<<NTRI * 4 + 8, 256, 0, stream>>>(Mpart, Spart, qpart, S);
    finalize<<<1, 256, 0, stream>>>(qpart, S, out);
}

// Round 19
// 55.200 us; speedup vs baseline: 1.7574x; 1.0248x over previous
//
#include <hip/hip_runtime.h>

#define N_CLS 8192
#define DIM   2048          // feature dim; M = Xn^T Xn is DIM x DIM
#define XTROW 4096          // xt row bytes: 8192 fp4 elems / 2
#define BKB   128           // K-tile bytes per row = 256 fp4 elems
#define NBT   16            // DIM/128 tile grid
#define NTRI  136           // NBT*(NBT+1)/2 triangular 128x128 tiles
#define NCH   4             // K chunks (8192 elems -> 4 x 2048)
#define NKT   8             // K-tiles per chunk (1024 B / 128 B)
#define MSLOT 16384         // u16 elems per partial 128x128 tile (32 KB)

typedef __attribute__((ext_vector_type(16))) float f32x16;
typedef __attribute__((ext_vector_type(8)))  int   i32x8;

__device__ __forceinline__ void load16(const char* g, char* l) {
    __builtin_amdgcn_global_load_lds(
        (const __attribute__((address_space(1))) void*)g,
        (__attribute__((address_space(3))) void*)l, 16, 0, 0);
}

__device__ __forceinline__ unsigned short f2bf(float f) {
    union { float f; unsigned u; } a; a.f = f;
    return (unsigned short)((a.u + 0x7fffu + ((a.u >> 16) & 1u)) >> 16);
}
__device__ __forceinline__ float bf2f(unsigned short u) {
    union { unsigned u; float f; } a; a.u = ((unsigned)u) << 16;
    return a.f;
}
// ---- e2m1 encode: nearest of {0,.5,1,1.5,2,3,4,6} with sign ----
__device__ __forceinline__ unsigned enc1(float v, float sc) {
    float a = fabsf(v) * sc;
    unsigned c = (a >= 0.25f) + (a >= 0.75f) + (a >= 1.25f) + (a >= 1.75f) +
                 (a >= 2.5f)  + (a >= 3.5f)  + (a >= 5.0f);
    return c | ((__float_as_uint(v) >> 28) & 8u);
}

// ---------------- kernel 1: per-row 1/||row|| ----------------
__global__ __launch_bounds__(256) void row_norms(const float* __restrict__ x,
                                                 float* __restrict__ inv) {
    const int wid = threadIdx.x >> 6, lane = threadIdx.x & 63;
    const int row = blockIdx.x * 4 + wid;
    const float4* xr = reinterpret_cast<const float4*>(x + (size_t)row * DIM);
    float s = 0.0f;
#pragma unroll
    for (int k = 0; k < 8; ++k) {
        float4 v = xr[lane + 64 * k];
        s += v.x*v.x + v.y*v.y + v.z*v.z + v.w*v.w;
    }
#pragma unroll
    for (int off = 32; off > 0; off >>= 1) s += __shfl_down(s, off);
    if (lane == 0) inv[row] = 1.0f / fmaxf(sqrtf(s), 1e-12f);
}

// ---- kernel 2: transpose+quantize, nibble-packed LDS (proven r15) ----
__global__ __launch_bounds__(256) void transpose_quant(const float* __restrict__ x,
                                                       const float* __restrict__ inv,
                                                       unsigned char* __restrict__ xt,
                                                       float* __restrict__ Spart) {
    __shared__ unsigned short nib[128][40];   // [row][col-group]; 4 cols per u16
    __shared__ float invs[128];
    __shared__ float sred[4][128];
    const int ic = blockIdx.x, dc = blockIdx.y;
    const int t = threadIdx.x;
    if (t < 128) invs[t] = inv[ic * 128 + t];
    __syncthreads();
    float sc0 = 0.f, sc1 = 0.f, sc2 = 0.f, sc3 = 0.f;
    const int cg = t & 31;                 // loop-invariant column group (4 cols)
#pragma unroll
    for (int it = 0; it < 16; ++it) {
        const int r = it * 8 + (t >> 5);   // 0..127
        float4 v = *reinterpret_cast<const float4*>(
            x + (size_t)(ic * 128 + r) * DIM + dc * 128 + cg * 4);
        const float iv = invs[r];
        float n0 = v.x * iv, n1 = v.y * iv, n2 = v.z * iv, n3 = v.w * iv;
        nib[r][cg] = (unsigned short)(enc1(n0, 64.0f) | (enc1(n1, 64.0f) << 4) |
                                      (enc1(n2, 64.0f) << 8) | (enc1(n3, 64.0f) << 12));
        sc0 += n0; sc1 += n1; sc2 += n2; sc3 += n3;
    }
    sc0 += __shfl_down(sc0, 32); sc1 += __shfl_down(sc1, 32);
    sc2 += __shfl_down(sc2, 32); sc3 += __shfl_down(sc3, 32);
    const int lane = t & 63, w = t >> 6;
    if (lane < 32) {
        sred[w][lane * 4 + 0] = sc0; sred[w][lane * 4 + 1] = sc1;
        sred[w][lane * 4 + 2] = sc2; sred[w][lane * 4 + 3] = sc3;
    }
    __syncthreads();
    if (t < 128)
        Spart[(size_t)ic * DIM + dc * 128 + t] =
            sred[0][t] + sred[1][t] + sred[2][t] + sred[3][t];

    // gather: thread owns (d, half); assemble 32 bytes along i for fixed d
    const int d = t & 127, half = t >> 7, dg = d >> 2, sh = (d & 3) * 4;
    unsigned wv[8];
#pragma unroll
    for (int j = 0; j < 8; ++j) {
        unsigned wd = 0;
#pragma unroll
        for (int b = 0; b < 4; ++b) {
            const int i0 = half * 64 + (j * 4 + b) * 2;
            unsigned lo = (nib[i0][dg] >> sh) & 0xFu;
            unsigned hi = (nib[i0 + 1][dg] >> sh) & 0xFu;
            wd |= (lo | (hi << 4)) << (8 * b);
        }
        wv[j] = wd;
    }
    const size_t off = (size_t)(dc * 128 + d) * XTROW + ic * 64 + half * 32;
    *reinterpret_cast<int4*>(xt + off)      = make_int4((int)wv[0], (int)wv[1], (int)wv[2], (int)wv[3]);
    *reinterpret_cast<int4*>(xt + off + 16) = make_int4((int)wv[4], (int)wv[5], (int)wv[6], (int)wv[7]);
}

// read one 16-byte (K=64, fp4) fragment from a swizzled LDS row; dup into both halves
__device__ __forceinline__ i32x8 rdfrag4(const char* rowp, int cc, int swz) {
    int4 d = *reinterpret_cast<const int4*>(rowp + (((cc) ^ swz) << 4));
    i32x8 r;
    r[0] = d.x; r[1] = d.y; r[2] = d.z; r[3] = d.w;
    r[4] = d.x; r[5] = d.y; r[6] = d.z; r[7] = d.w;
    return r;
}
#define MFMA4(A, B, C) __builtin_amdgcn_mfma_scale_f32_32x32x64_f8f6f4( \
    (A), (B), (C), 4, 4, 0, 0x7F7F7F7F, 0, 0x7F7F7F7F)

// ---- kernel 3: partial M-tile SYRK (r11 structure), K-split x4, bf16 out (proven r15) ----
__global__ __launch_bounds__(256) void msyrk_part(const char* __restrict__ xt,
                                                  unsigned short* __restrict__ Mpart) {
    __shared__ __align__(16) char As[128 * BKB];   // 16 KiB
    __shared__ __align__(16) char Bs[128 * BKB];   // 16 KiB

    const int tile = blockIdx.x >> 2, ch = blockIdx.x & 3;
    int bi = 0, rem = tile;                     // triangle decode, bi <= bj
    while (rem >= NBT - bi) { rem -= NBT - bi; ++bi; }
    const int bj = bi + rem;

    const int tid = threadIdx.x;
    const int lane = tid & 63, wid = tid >> 6;
    const int wr = wid >> 1, wc = wid & 1;      // wave grid 2 x 2, each 64x64

    const int srow = lane >> 3;
    const int gch  = ((lane & 7) ^ srow) << 4;
    const char* gA = xt + (size_t)(bi * 128 + wid * 32 + srow) * XTROW + ch * 1024 + gch;
    const char* gB = xt + (size_t)(bj * 128 + wid * 32 + srow) * XTROW + ch * 1024 + gch;

    const int lr = lane & 31, hi = lane >> 5, swz = lane & 7;
    const char* arow = As + (wr * 64 + lr) * BKB;
    const char* brow = Bs + (wc * 64 + lr) * BKB;

    f32x16 acc[2][2];
#pragma unroll
    for (int m = 0; m < 2; ++m)
#pragma unroll
        for (int n = 0; n < 2; ++n)
#pragma unroll
            for (int r = 0; r < 16; ++r) acc[m][n][r] = 0.0f;

    for (int t = 0; t < NKT; ++t) {
#pragma unroll
        for (int q = 0; q < 4; ++q)
            load16(gA + (size_t)(q * 8) * XTROW + t * BKB, &As[wid * 4096 + q * 1024]);
#pragma unroll
        for (int q = 0; q < 4; ++q)
            load16(gB + (size_t)(q * 8) * XTROW + t * BKB, &Bs[wid * 4096 + q * 1024]);
        __syncthreads();
#pragma unroll
        for (int s = 0; s < 4; ++s) {
            i32x8 af[2], bf[2];
#pragma unroll
            for (int m = 0; m < 2; ++m)
                af[m] = rdfrag4(arow + m * 32 * BKB, 2 * s + hi, swz);
#pragma unroll
            for (int n = 0; n < 2; ++n)
                bf[n] = rdfrag4(brow + n * 32 * BKB, 2 * s + hi, swz);
#pragma unroll
            for (int m = 0; m < 2; ++m)
#pragma unroll
                for (int n = 0; n < 2; ++n)
                    acc[m][n] = MFMA4(af[m], bf[n], acc[m][n]);
        }
        __syncthreads();
    }

    unsigned short* outp = Mpart + (size_t)(tile * NCH + ch) * MSLOT;
#pragma unroll
    for (int m = 0; m < 2; ++m)
#pragma unroll
        for (int n = 0; n < 2; ++n)
#pragma unroll
            for (int rq = 0; rq < 4; ++rq) {
                ushort4 v;
                v.x = f2bf(acc[m][n][rq * 4 + 0]);
                v.y = f2bf(acc[m][n][rq * 4 + 1]);
                v.z = f2bf(acc[m][n][rq * 4 + 2]);
                v.w = f2bf(acc[m][n][rq * 4 + 3]);
                *reinterpret_cast<ushort4*>(outp + ((m * 2 + n) * 4 + rq) * 1024 + tid * 4) = v;
            }
}

// ---- kernel 4: qcombine (blocks < NTRI*4) + scombine (blocks >= NTRI*4) ----
__global__ __launch_bounds__(256) void qscombine(const unsigned short* __restrict__ Mpart,
                                                 const float* __restrict__ Spart,
                                                 float* __restrict__ qpart,
                                                 float* __restrict__ S) {
    if (blockIdx.x >= NTRI * 4) {               // scombine: 8 blocks
        const int d = (blockIdx.x - NTRI * 4) * 256 + threadIdx.x;
        float s = 0.0f;
        for (int ic = 0; ic < 64; ++ic) s += Spart[(size_t)ic * DIM + d];
        S[d] = s;
        return;
    }
    const int tile = blockIdx.x >> 2, q4 = blockIdx.x & 3;
    int bi = 0, rem = tile;
    while (rem >= NBT - bi) { rem -= NBT - bi; ++bi; }
    const int bj = bi + rem;
    const float w = (bi == bj) ? 1.0f : 2.0f;
    const float inv = 1.0f / 4096.0f;           // raw = 4096 * M (scale 64^2)

    const unsigned short* base = Mpart + (size_t)tile * NCH * MSLOT;
    float s = 0.0f;
#pragma unroll
    for (int k = 0; k < 4; ++k) {
        const int p = q4 * 4096 + k * 1024 + threadIdx.x * 4;
        ushort4 a0 = *reinterpret_cast<const ushort4*>(base + 0 * MSLOT + p);
        ushort4 a1 = *reinterpret_cast<const ushort4*>(base + 1 * MSLOT + p);
        ushort4 a2 = *reinterpret_cast<const ushort4*>(base + 2 * MSLOT + p);
        ushort4 a3 = *reinterpret_cast<const ushort4*>(base + 3 * MSLOT + p);
        float vx = (bf2f(a0.x) + bf2f(a1.x) + bf2f(a2.x) + bf2f(a3.x)) * inv;
        float vy = (bf2f(a0.y) + bf2f(a1.y) + bf2f(a2.y) + bf2f(a3.y)) * inv;
        float vz = (bf2f(a0.z) + bf2f(a1.z) + bf2f(a2.z) + bf2f(a3.z)) * inv;
        float vw = (bf2f(a0.w) + bf2f(a1.w) + bf2f(a2.w) + bf2f(a3.w)) * inv;
        s += vx * vx + vy * vy + vz * vz + vw * vw;
    }
#pragma unroll
    for (int off = 32; off > 0; off >>= 1) s += __shfl_down(s, off);
    __shared__ float red[4];
    if ((threadIdx.x & 63) == 0) red[threadIdx.x >> 6] = s;
    __syncthreads();
    if (threadIdx.x == 0)
        qpart[blockIdx.x] = w * (red[0] + red[1] + red[2] + red[3]);
}

// ---------------- kernel 5: finalize (proven r8 formula) ----------------
__global__ __launch_bounds__(256) void finalize(const float* __restrict__ qpart,
                                                const float* __restrict__ S,
                                                float* __restrict__ out) {
    const int t = threadIdx.x;
    float q = 0.0f;
    for (int i = t; i < NTRI * 4; i += 256) q += qpart[i];
    float s2 = 0.0f;
#pragma unroll
    for (int k = 0; k < 8; ++k) {
        float v = S[t + 256 * k];
        s2 += v * v;
    }
#pragma unroll
    for (int off = 32; off > 0; off >>= 1) {
        q  += __shfl_down(q, off);
        s2 += __shfl_down(s2, off);
    }
    __shared__ float redq[4], reds[4];
    if ((t & 63) == 0) { redq[t >> 6] = q; reds[t >> 6] = s2; }
    __syncthreads();
    if (t == 0) {
        double Q  = (double)redq[0] + redq[1] + redq[2] + redq[3];
        double S2 = (double)reds[0] + reds[1] + reds[2] + reds[3];
        const double N = 8192.0, NN1 = 8192.0 * 8191.0;
        double ans = (N + exp(-2.0) * (NN1 + 2.0 * (S2 - N) + 2.0 * (Q - N))) / NN1;
        out[0] = (float)ans;
    }
}

extern "C" void kernel_launch(void* const* d_in, const int* in_sizes, int n_in,
                              void* d_out, int out_size, void* d_ws, size_t ws_size,
                              hipStream_t stream) {
    const float* x = (const float*)d_in[0];
    float* out = (float*)d_out;
    // ws layout: xt 8MB | inv 32KB | Spart 512KB | S 8KB | Mpart(bf16) 17.8MB | qpart
    unsigned char* xt = (unsigned char*)d_ws;
    float* inv   = (float*)((char*)d_ws + (size_t)DIM * XTROW);
    float* Spart = inv + N_CLS;
    float* S     = Spart + (size_t)64 * DIM;
    unsigned short* Mpart = (unsigned short*)(S + DIM);
    float* qpart = (float*)(Mpart + (size_t)NTRI * NCH * MSLOT);

    row_norms<<<N_CLS / 4, 256, 0, stream>>>(x, inv);
    transpose_quant<<<dim3(64, 16), 256, 0, stream>>>(x, inv, xt, Spart);
    msyrk_part<<<NTRI * NCH, 256, 0, stream>>>((const char*)xt, Mpart);
    qscombine<<<NTRI * 4 + 8, 256, 0, stream>>>(Mpart, Spart, qpart, S);
    finalize<<<1, 256, 0, stream>>>(qpart, S, out);
}